// Round 15
// baseline (731.903 us; speedup 1.0000x reference)
//
#include <hip/hip_runtime.h>
#include <hip/hip_bf16.h>

// STU forward, R15: R14 + 15-step boundary chain fused into ONE kernel with a
// software grid barrier (32 co-resident blocks, agent-scope release/acquire).
// Sizes: B=2, L=1024, K=24(x2), D=512, K_U=3, K_Y=2.

typedef unsigned short u16;
typedef __attribute__((ext_vector_type(8))) short  vshort8;
typedef __attribute__((ext_vector_type(4))) short  vshort4;
typedef __attribute__((ext_vector_type(4))) float  f32x4;
typedef __attribute__((ext_vector_type(4))) unsigned int vuint4;

__device__ __forceinline__ u16 f2b(float x) {
  __hip_bfloat16 h = __float2bfloat16(x);
  return __builtin_bit_cast(u16, h);
}
__device__ __forceinline__ float b2f(u16 x) {
  unsigned int u = ((unsigned int)x) << 16;
  return __builtin_bit_cast(float, u);
}

// async global->LDS, 16B per lane; LDS dest = wave-uniform base + lane*16
__device__ __forceinline__ void gll16(const u16* g, u16* l) {
  __builtin_amdgcn_global_load_lds((__attribute__((address_space(1))) void*)g,
                                   (__attribute__((address_space(3))) void*)l,
                                   16, 0, 0);
}

// A2T layout strides: [b:2][cj:8][kh:48][o:512][sp:128]
#define A2T_B  25165824
#define A2T_CJ 3145728
#define A2T_KH 65536

// ---------------------------------------------------------------------------
// Shared MFMA GEMM template. C[m,n] = sum_k A[m,k]*Bmat[n,k].
//  V0 GEMM1: 128x256 tile, 512 thr; A=X(2048x512) B=W1(26112x512); grid 1632
//  V1 CONV : A=Wtoep strip (d=bm-cj), B=A2T; 1-D grid 1152, splitK=8
//  V2 ZGEMM: A=gather(ybf), B=Top; 1-D grid 544 triangular, 16 slices
//  V3 FIXUP: A=Abnd(64x1024), B=Top[j+1] rows -> out = acc + zf
//  V5 SGEMM: A=Top[1+bz], B=S^c^T from P; -> Top[c+1+bz] + P[c+1+bz] (dual)
//  V6 UGEMM: A=Wm(64x1024), B=S32 rows -> ubuf = acc + w_{c+1} (f32)
//  V7 ODD  : A=Abnd even rows, B=S32 rows -> Abnd odd rows = acc + w_{2k}
// ---------------------------------------------------------------------------
struct GB {
  const u16* A; const u16* B;
  float* Cf; u16* Cb;
  const float* zf; float* out;
  u16* A2T; u16* Au;
  const u16* zp;
  u16* Pb; int cidx; int pthr;
  int M, N;
};

template<int V>
__global__ __launch_bounds__(V == 0 ? 512 : 256) void g2(GB a) {
  const int tid = threadIdx.x;
  int bn = blockIdx.x, bm = blockIdx.y;
  int zz = blockIdx.z;
  int cj = 0, cb = 0, cd = 0, slot = 0;
  int kbeg = 0, kend = 0;
  if (V == 0) {
    int f = blockIdx.x;
    int o = (f & 7) * 204 + (f >> 3);          // 1632 = 8 x 204
    bm = o & 15; bn = o >> 4; kend = 512;
  }
  if (V == 1) {
    int f = blockIdx.x;
    int o = (f & 7) * 144 + (f >> 3);          // 1152 = 8 x 144
    const int offs1[8] = {0, 256, 480, 672, 832, 960, 1056, 1120};
    cj = 0;
    if (o >= offs1[1]) cj = 1;
    if (o >= offs1[2]) cj = 2;
    if (o >= offs1[3]) cj = 3;
    if (o >= offs1[4]) cj = 4;
    if (o >= offs1[5]) cj = 5;
    if (o >= offs1[6]) cj = 6;
    if (o >= offs1[7]) cj = 7;
    int r = o - offs1[cj];
    int run = 8 - cj;
    int combo = r / run;                       // [0,32): (zzc, bn)
    bm = cj + (r - combo * run);
    int zzc = combo >> 2; bn = combo & 3;
    cb = zzc & 1; cd = bm - cj;
    slot = zzc * 8 + cj;
    kbeg = (zzc >> 1) * 1536; kend = kbeg + 1536;
  }
  if (V == 2) {
    int f = blockIdx.x;
    int o = (f & 7) * 68 + (f >> 3);           // 544 = 8 x 68
    const int offs2[16] = {0, 64, 124, 180, 232, 280, 324, 364,
                           400, 432, 460, 484, 504, 520, 532, 540};
    int s = 0;
#pragma unroll
    for (int c = 1; c < 16; ++c)
      if (o >= offs2[c]) s = c;
    int r = o - offs2[s];
    bm = s + (r >> 2); bn = r & 3;
    zz = s;
    kbeg = s * 1024; kend = kbeg + 1024;       // s<=bm guarantees validity
  }
  const int m0 = bm * 128;
  const int n0 = (V == 0) ? bn * 256 : bn * 128;
  if (V == 3 || V == 5 || V == 6 || V == 7) kend = 1024;

  __shared__ u16 smem[V == 0 ? 24576 : 16384];
  f32x4 acc[4][4];
#pragma unroll
  for (int i = 0; i < 4; i++)
#pragma unroll
    for (int j = 0; j < 4; j++) acc[i][j] = f32x4{0.f, 0.f, 0.f, 0.f};

  const int lane = tid & 63, wv = tid >> 6;
  const int wr = (V == 0) ? (wv >> 2) : (wv >> 1);
  const int wc = (V == 0) ? (wv & 3) : (wv & 1);
  const u16* Ap = a.A;
  if (V == 5) Ap = a.A + (size_t)zz * 524288;
  const u16* zpl = a.zp + lane * 8;

  auto gaddrA = [&](int it, int k0) -> const u16* {
    int lrow = (it * 4 + wv) * 16 + (lane & 15);
    int kk = k0 + ((lane >> 4) << 3);
    if (V == 1) return Ap + (size_t)cd * 786432 + (size_t)lrow * 6144 + kk;
    if (V == 2) {
      int m = m0 + lrow, j = m >> 6, b = (m >> 5) & 1, c = m & 31;
      int tau = kk >> 9, p = kk & 511;
      if (tau > j) return zpl;
      return Ap + (size_t)(b * 1024 + c * 32 + j - tau) * 512 + p;
    }
    if (V == 3) { int m = m0 + lrow; return (m < a.M) ? Ap + (size_t)m * 1024 + kk : zpl; }
    if (V == 5) return Ap + (size_t)(m0 + lrow) * 1024 + kk;
    if (V == 6) return (lrow < 64) ? Ap + (size_t)lrow * 1024 + kk : zpl;
    // V7
    if (lrow < 32) {
      int b = lrow & 1, k2 = lrow >> 1;
      return Ap + (size_t)(b * 32 + 2 * k2) * 1024 + kk;
    }
    return zpl;
  };
  auto gaddrB = [&](int it, int k0) -> const u16* {
    int lrow = (it * 4 + wv) * 16 + (lane & 15);
    int kk = k0 + ((lane >> 4) << 3);
    int n = n0 + lrow;
    if (V == 1) {
      int kh = kk >> 7, sp = kk & 127;
      return a.B + (size_t)cb * A2T_B + (size_t)cj * A2T_CJ
           + (size_t)kh * A2T_KH + (size_t)n * 128 + sp;
    }
    if (V == 2) {
      int tau = kk >> 9, p = kk & 511;
      return a.B + (size_t)tau * 524288 + (size_t)n * 1024 + p;
    }
    if (V == 3) {
      int jn = n >> 9, o = n & 511;
      return a.B + (size_t)(jn + 1) * 524288 + (size_t)o * 1024 + kk;
    }
    if (V == 5) {
      // B[n][kk] = S^c^T[n][kk] from P
      return (kk < 512)
          ? a.Pb + (size_t)a.cidx * 524288 + (size_t)n * 512 + kk
          : a.Pb + (size_t)(a.cidx - 1) * 524288 + (size_t)n * 512 + (kk - 512);
    }
    // V6/V7: rows of S32 = [Top32 ; Top31]
    return (n < 512)
        ? a.B + (size_t)32 * 524288 + (size_t)n * 1024 + kk
        : a.B + (size_t)31 * 524288 + (size_t)(n - 512) * 1024 + kk;
  };

  auto stage = [&](int c, int k0) {
    if (V == 0) {
      int kk = k0 + ((lane >> 4) << 3);
      int lrowA = wv * 16 + (lane & 15);
      gll16(Ap + (size_t)(m0 + lrowA) * 512 + kk, smem + c * 4096 + wv * 512);
#pragma unroll
      for (int it = 0; it < 2; ++it) {
        int lrowB = (it * 8 + wv) * 16 + (lane & 15);
        gll16(a.B + (size_t)(n0 + lrowB) * 512 + kk,
              smem + 8192 + c * 8192 + (it * 8 + wv) * 512);
      }
    } else {
#pragma unroll
      for (int it = 0; it < 2; ++it) {
        int weff = wv + it * 4;
        gll16(gaddrA(it, k0), smem + c * 4096 + weff * 512);
        gll16(gaddrB(it, k0), smem + 8192 + c * 4096 + weff * 512);
      }
    }
  };

  if (kbeg < kend) stage(0, kbeg);
  __syncthreads();                 // drains the prologue stage
  int cur = 0;
  for (int k0 = kbeg; k0 < kend; k0 += 32) {
    if (k0 + 32 < kend) stage(cur ^ 1, k0 + 32);   // async prefetch next tile
    vshort8 af[4], bf_[4];
#pragma unroll
    for (int s = 0; s < 4; s++) {
      af[s] = *(const vshort8*)&smem[cur * 4096 +
                (((wr * 4 + s) * 4 + (lane >> 4)) * 16 + (lane & 15)) * 8];
      if (V == 0)
        bf_[s] = *(const vshort8*)&smem[8192 + cur * 8192 +
                  (((wc * 4 + s) * 4 + (lane >> 4)) * 16 + (lane & 15)) * 8];
      else
        bf_[s] = *(const vshort8*)&smem[8192 + cur * 4096 +
                  (((wc * 4 + s) * 4 + (lane >> 4)) * 16 + (lane & 15)) * 8];
    }
#pragma unroll
    for (int i = 0; i < 4; i++)
#pragma unroll
      for (int j = 0; j < 4; j++)
        acc[i][j] = __builtin_amdgcn_mfma_f32_16x16x32_bf16(af[i], bf_[j], acc[i][j], 0, 0, 0);
    __syncthreads();               // drains prefetch + protects buffer swap
    cur ^= 1;
  }

  // ---- epilogue ----
  if (V == 0 && bn < 96) {
    // 4 phases; phase p handles n-cols [n0+p*64, +64) via LDS transpose.
    const int strd = 136;
    const int b = m0 >> 10;
    const int cjw = (m0 & 1023) >> 7;
#pragma unroll
    for (int p = 0; p < 4; ++p) {
      __syncthreads();
      if (wc == p) {
#pragma unroll
        for (int i = 0; i < 4; i++) {
#pragma unroll
          for (int j = 0; j < 4; j++) {
            f32x4 v = acc[i][j];
            int mloc = wr * 64 + i * 16 + ((lane >> 4) << 2);  // sp in [0,128)
            int phys = j * 16 + (lane & 15);                   // n-off in [0,64)
            vshort4 pk = { (short)f2b(v[0]), (short)f2b(v[1]),
                           (short)f2b(v[2]), (short)f2b(v[3]) };
            *(vshort4*)&smem[phys * strd + mloc] = pk;
          }
        }
      }
      __syncthreads();
      int rowp = tid >> 3, t8 = tid & 7;
      int n = n0 + p * 64 + rowp;
      int o = n & 511, kh = n >> 9;
      u16* dst = a.A2T + (size_t)b * A2T_B + (size_t)cjw * A2T_CJ
               + (size_t)kh * A2T_KH + (size_t)o * 128 + t8 * 16;
      const u16* srcl = &smem[rowp * strd + t8 * 16];
      *(vuint4*)(dst)     = *(const vuint4*)(srcl);
      *(vuint4*)(dst + 8) = *(const vuint4*)(srcl + 8);
    }
    return;
  }

#pragma unroll
  for (int i = 0; i < 4; i++) {
    int em = m0 + wr * 64 + i * 16 + ((lane >> 4) << 2);
#pragma unroll
    for (int j = 0; j < 4; j++) {
      int n = n0 + wc * 64 + j * 16 + (lane & 15);
      f32x4 v = acc[i][j];
      if (V == 0) {
        int b = em >> 10, s = em & 1023;
        int jj = (n - 24576) >> 9, o = n & 511;
#pragma unroll
        for (int t = 0; t < 4; t++)
          a.Au[((size_t)(b * 3 + jj) * 1024 + (s + t)) * 512 + o] = f2b(v[t]);
      } else if (V == 1) {
        u16* C = a.Cb + (size_t)slot * 524288;
#pragma unroll
        for (int t = 0; t < 4; t++) C[(size_t)(em + t) * 512 + n] = f2b(v[t]);
      } else if (V == 2) {
        float* C = a.Cf + (size_t)zz * 1048576;
#pragma unroll
        for (int t = 0; t < 4; t++) C[(size_t)(em + t) * 512 + n] = v[t];
      } else if (V == 3) {
        int jj = n >> 9, oo = n & 511;
#pragma unroll
        for (int t = 0; t < 4; t++) {
          int m = em + t;
          if (m < a.M) {
            int b = m >> 5, c = m & 31;
            float zv = a.zf[(size_t)(jj * 64 + b * 32 + c) * 512 + oo];
            a.out[(size_t)b * 524288 + (size_t)(c * 32 + jj) * 512 + oo] = v[t] + zv;
          }
        }
      } else if (V == 5) {
        u16* C = a.Cb + (size_t)zz * 524288;
#pragma unroll
        for (int t = 0; t < 4; t++) C[(size_t)(em + t) * 1024 + n] = f2b(v[t]);
      } else if (V == 6) {
        int jrow = (n < 512) ? 31 : 30, oo = n & 511;
#pragma unroll
        for (int t = 0; t < 4; t++) {
          int m = em + t;
          if (m < 62) {
            int b = m & 1, c = m >> 1;
            a.Cf[(size_t)m * 1024 + n] =
                v[t] + a.zf[(size_t)(jrow * 64 + b * 32 + (c + 1)) * 512 + oo];
          }
        }
      } else { // V7: odd states
        int jrow = (n < 512) ? 31 : 30, oo = n & 511;
#pragma unroll
        for (int t = 0; t < 4; t++) {
          int m = em + t;
          if (m < 32) {
            int b = m & 1, k2 = m >> 1;
            float val = v[t] + a.zf[(size_t)(jrow * 64 + b * 32 + 2 * k2) * 512 + oo];
            a.Cb[(size_t)(b * 32 + 2 * k2 + 1) * 1024 + n] = f2b(val);
          }
        }
      }
    }
  }

  // V5 dual-write: P[c+1+zz][n][m] = C[m][n] via LDS transpose (2 passes)
  if (V == 5) {
    if (zz >= a.pthr) {
      const int strd = 136;
      u16* Pout = a.Pb + (size_t)(a.cidx + 1 + zz) * 524288;
#pragma unroll
      for (int p = 0; p < 2; ++p) {
        __syncthreads();
        if (wc == p) {
#pragma unroll
          for (int i = 0; i < 4; i++) {
#pragma unroll
            for (int j = 0; j < 4; j++) {
              f32x4 v = acc[i][j];
              int mloc = wr * 64 + i * 16 + ((lane >> 4) << 2);  // m-off [0,128)
              int phys = j * 16 + (lane & 15);                   // n-off [0,64)
              vshort4 pk = { (short)f2b(v[0]), (short)f2b(v[1]),
                             (short)f2b(v[2]), (short)f2b(v[3]) };
              *(vshort4*)&smem[phys * strd + mloc] = pk;
            }
          }
        }
        __syncthreads();
        int rowp = tid >> 2, t4 = tid & 3;
        u16* dst = Pout + (size_t)(n0 + p * 64 + rowp) * 512 + m0 + t4 * 32;
        const u16* srcl = &smem[rowp * strd + t4 * 32];
#pragma unroll
        for (int q = 0; q < 4; ++q)
          *(vuint4*)(dst + q * 8) = *(const vuint4*)(srcl + q * 8);
      }
    }
  }
}

// ---------------------------------------------------------------------------
// prep / glue kernels
// ---------------------------------------------------------------------------
// phis[tau*48 + kf]: kf<24 -> phi_s[tau,kf]; kf>=24 -> phi_s[tau,kf-24]*(-1)^tau
__global__ void k_prep_phis(const float* __restrict__ phi, const float* __restrict__ sigma,
                            float* __restrict__ phis) {
  int i = blockIdx.x * 256 + threadIdx.x;
  if (i >= 1024 * 48) return;
  int tau = i / 48, kf = i % 48, k = (kf >= 24) ? kf - 24 : kf;
  float v = phi[tau * 24 + k] * powf(sigma[k], 0.25f);
  if (kf >= 24 && (tau & 1)) v = -v;
  phis[i] = v;
}

// fused: X convert (vec4), W1 convert (vec4 x4 rounds), Wtoep build (vec8)
__global__ void k_prep_all(const float* __restrict__ u, const float* __restrict__ Mp,
                           const float* __restrict__ Mm, const float* __restrict__ Mu,
                           const float* __restrict__ phis,
                           u16* __restrict__ X, u16* __restrict__ W1,
                           u16* __restrict__ Wtoep) {
  int gid = blockIdx.x * 256 + threadIdx.x;   // [0, 1048576)
  if (gid < 262144) {
    int i4 = gid * 4;
    f32x4 v = *(const f32x4*)(u + i4);
    vshort4 pk = { (short)f2b(v[0]), (short)f2b(v[1]), (short)f2b(v[2]), (short)f2b(v[3]) };
    *(vshort4*)(X + i4) = pk;
  }
#pragma unroll
  for (int r = 0; r < 4; ++r) {
    int item = gid + r * 1048576;
    if (item < 3342336) {
      int i4 = item * 4;
      const float* src; int off;
      if (i4 < 6291456) { src = Mp; off = i4; }
      else if (i4 < 12582912) { src = Mm; off = i4 - 6291456; }
      else { src = Mu; off = i4 - 12582912; }
      f32x4 v = *(const f32x4*)(src + off);
      vshort4 pk = { (short)f2b(v[0]), (short)f2b(v[1]), (short)f2b(v[2]), (short)f2b(v[3]) };
      *(vshort4*)(W1 + i4) = pk;
    }
  }
  if (gid < 786432) {
    int i = gid * 8;
    int kap = i % 6144, row = i / 6144;
    int tp = row & 127, d = row >> 7;
    int kh = kap >> 7, sp = kap & 127;
    int tau0 = d * 128 + tp - sp;
    u16 vals[8];
#pragma unroll
    for (int e = 0; e < 8; ++e) {
      int tau = tau0 - e;
      vals[e] = (tau >= 0 && tau < 1024) ? f2b(phis[tau * 48 + kh]) : (u16)0;
    }
    *(vuint4*)(Wtoep + i) = *(const vuint4*)vals;
  }
}

// Top[0]=[I|0], Top[1]=[M1|M2]; P[0]=Top[0]^T, P[1]=Top[1]^T
__global__ void k_initTop(const float* __restrict__ my, u16* __restrict__ Top,
                          u16* __restrict__ P) {
  int i = blockIdx.x * 256 + threadIdx.x;
  if (i >= 2097152) return;
  if (i < 1048576) {
    int mat = i >> 19, rem = i & 524287, o = rem >> 10, k = rem & 1023;
    u16 v;
    if (mat == 0) v = (k == o) ? (u16)0x3F80 : (u16)0;
    else v = (k < 512) ? f2b(my[o * 512 + k]) : f2b(my[262144 + o * 512 + (k - 512)]);
    Top[i] = v;
  } else {
    int j = i - 1048576;
    int mat = j >> 19, rem = j & 524287, n = rem >> 9, m = rem & 511;
    u16 v;
    if (mat == 0) v = (n == m) ? (u16)0x3F80 : (u16)0;
    else v = (n < 512) ? f2b(my[m * 512 + n]) : f2b(my[262144 + m * 512 + (n - 512)]);
    P[(size_t)mat * 524288 + (size_t)n * 512 + m] = v;
  }
}

__device__ __forceinline__ void addp(float* acc, vuint4 v) {
  const unsigned int* vu = (const unsigned int*)&v;
#pragma unroll
  for (int e = 0; e < 4; ++e) {
    unsigned int pw = vu[e];
    acc[2 * e]     += __builtin_bit_cast(float, (pw & 0xffffu) << 16);
    acc[2 * e + 1] += __builtin_bit_cast(float, pw & 0xffff0000u);
  }
}

// ybf[b,t,og*8..] = sum_j Au[b,j,t-j,:] + (t>=2 ? valid bf16 conv partials : 0)
__global__ void k_combine(const u16* __restrict__ parts, const u16* __restrict__ Au,
                          u16* __restrict__ ybf) {
  int i = blockIdx.x * 256 + threadIdx.x;
  if (i >= 131072) return;
  int og = i & 63, t = (i >> 6) & 1023, b = i >> 16;
  float acc[8];
#pragma unroll
  for (int e = 0; e < 8; ++e) acc[e] = 0.f;
#pragma unroll
  for (int j = 0; j < 3; j++)
    if (t >= j)
      addp(acc, *(const vuint4*)(Au + ((size_t)(b * 3 + j) * 1024 + (t - j)) * 512 + og * 8));
  if (t >= 2) {
    int tp = t - 2, bmv = tp >> 7;
#pragma unroll
    for (int g = 0; g < 8; ++g) {
      if ((g & 1) != b) continue;
      const u16* base = parts + (size_t)(g * 8) * 524288 + (size_t)tp * 512 + og * 8;
      for (int j = 0; j <= bmv; ++j)
        addp(acc, *(const vuint4*)(base + (size_t)j * 524288));
    }
  }
  u16 o16[8];
#pragma unroll
  for (int e = 0; e < 8; ++e) o16[e] = f2b(acc[e]);
  *(vuint4*)(ybf + ((size_t)(b * 1024 + t)) * 512 + og * 8) = *(vuint4*)o16;
}

// fused: zf reduce + Wm extraction + bnd/Abnd zero-init
__global__ void k_zred(const float* __restrict__ zp, float* __restrict__ z,
                       u16* __restrict__ Wm, float* __restrict__ bnd,
                       u16* __restrict__ Abnd) {
  int i = blockIdx.x * 256 + threadIdx.x;
  if (i < 2048) bnd[i] = 0.f;
  if (i < 1024) { Abnd[i] = 0; Abnd[32768 + i] = 0; }
  if (i >= 1048576) return;
  int nsum = (i >> 16) + 1;        // bm = i>>16 in [0,16)
  float s = 0.f;
  for (int j = 0; j < nsum; ++j) s += zp[(size_t)j * 1048576 + i];
  z[i] = s;
  int m = i >> 9, jj = m >> 6, rem = m & 63, b = rem >> 5, c = rem & 31, oo = i & 511;
  if (jj == 31) Wm[(size_t)((c << 1) | b) * 1024 + oo] = f2b(s);
  if (jj == 30) Wm[(size_t)((c << 1) | b) * 1024 + 512 + oo] = f2b(s);
}

// fused 15-step chain: E_{k+1} = S64 E_k + u_{2k}; software grid barrier.
// 32 blocks (co-resident on 256-CU chip); ctr zeroed before launch.
__global__ __launch_bounds__(256) void k_chain(const u16* __restrict__ Top,
                                               const float* __restrict__ ubuf,
                                               float* __restrict__ bnd,
                                               u16* __restrict__ Abnd,
                                               int* __restrict__ ctr) {
  __shared__ float st[2048];
  const int tid = threadIdx.x;
  for (int k = 0; k < 15; ++k) {
    const float* s0 = bnd + (size_t)k * 2048;
    for (int j = tid; j < 2048; j += 256) st[j] = s0[j];
    __syncthreads();
    int q4 = blockIdx.x * 256 + tid;  // [0,8192)
    int q = q4 >> 2, quarter = q4 & 3;
    int b = q >> 10, kk = q & 1023;
    const u16* row = (kk < 512) ? Top + (size_t)34 * 524288 + (size_t)kk * 1024
                                : Top + (size_t)33 * 524288 + (size_t)(kk - 512) * 1024;
    const float* stb = st + b * 1024 + quarter * 256;
    const u16* rp = row + quarter * 256;
    float sum = 0.f;
    for (int t = 0; t < 32; ++t) {
      vuint4 v = *(const vuint4*)(rp + t * 8);
      const unsigned int* vu = (const unsigned int*)&v;
#pragma unroll
      for (int e = 0; e < 4; ++e) {
        unsigned int pw = vu[e];
        float lo = __builtin_bit_cast(float, (pw & 0xffffu) << 16);
        float hi = __builtin_bit_cast(float, pw & 0xffff0000u);
        sum += lo * stb[t * 8 + e * 2] + hi * stb[t * 8 + e * 2 + 1];
      }
    }
    sum += __shfl_xor(sum, 1);
    sum += __shfl_xor(sum, 2);
    if (quarter == 0) {
      float s = sum + ubuf[(size_t)(4 * k + b) * 1024 + kk];
      bnd[(size_t)(k + 1) * 2048 + b * 1024 + kk] = s;
      Abnd[(size_t)(b * 32 + 2 * k + 2) * 1024 + kk] = f2b(s);
    }
    // ---- software grid barrier (release/acquire, agent scope) ----
    __threadfence();
    __syncthreads();
    if (tid == 0) {
      __hip_atomic_fetch_add(ctr, 1, __ATOMIC_RELEASE, __HIP_MEMORY_SCOPE_AGENT);
      while (__hip_atomic_load(ctr, __ATOMIC_ACQUIRE, __HIP_MEMORY_SCOPE_AGENT)
             < 32 * (k + 1)) {}
      __threadfence();
    }
    __syncthreads();
  }
}

// ---------------------------------------------------------------------------
extern "C" void kernel_launch(void* const* d_in, const int* in_sizes, int n_in,
                              void* d_out, int out_size, void* d_ws, size_t ws_size,
                              hipStream_t stream) {
  const float* u     = (const float*)d_in[0];
  const float* Mu    = (const float*)d_in[1];
  const float* Mp    = (const float*)d_in[2];
  const float* Mm    = (const float*)d_in[3];
  const float* my    = (const float*)d_in[4];
  const float* sigma = (const float*)d_in[5];
  const float* phi   = (const float*)d_in[6];
  float* out = (float*)d_out;

  char* ws = (char*)d_ws;
  size_t off = 0;
  auto alc = [&](size_t b) { size_t p = off; off = (off + b + 255) & ~(size_t)255; return p; };
  u16*  X     = (u16*)(ws + alc(2097152));
  u16*  Wtoep = (u16*)(ws + alc(12582912));    // 8 d x 128 x 6144
  u16*  A2T   = (u16*)(ws + alc(100663296));   // [b][cj][kh][o][sp]
  u16*  Au    = (u16*)(ws + alc(6291456));
  u16*  W1    = (u16*)(ws + alc(26738688));    // 26112x512; parts region spans W1+tail
  char* ptail = ws + alc(40370176); (void)ptail; // W1+tail = 64 MiB exactly
  float* phis = (float*)(ws + alc(196608));    // [1024 tau][48 kf] f32
  float* bnd  = (float*)(ws + alc(131072));    // 16 even states x 2048 f32
  u16*  Abnd  = (u16*)(ws + alc(131072));      // 64 x 1024 bf16 boundary states
  u16*  Wm    = (u16*)(ws + alc(131072));      // 64 x 1024 bf16 w_c
  float* ubuf = (float*)(ws + alc(262144));    // 64 x 1024 f32 u_c
  u16*  zpad  = (u16*)(ws + alc(32768));       // zero page for predicated lanes
  int*  ctr   = (int*)(ws + alc(256));         // software-barrier counter
  if (off > ws_size) return;
  // lifetime-disjoint aliases:
  u16*  partsBf = (u16*)W1;                    // 64 conv slots x [1024][512] bf16 = 64 MiB
  float* zparts = (float*)W1;                  // 16 zgemm slots x 4 MiB f32 = 64 MiB
  u16*  ybf = A2T;                             // 2 MiB (after conv)
  float* zf = (float*)((char*)A2T + (4 << 20));
  u16*  Top = (u16*)((char*)A2T + (size_t)(8 << 20));   // 35 slots x 1 MiB (0..32,33=H63,34=H64)
  u16*  P   = (u16*)((char*)A2T + (size_t)(44 << 20));  // 33 slots x 1 MiB (Top^T)

  hipMemsetAsync(zpad, 0, 32768, stream);
  hipMemsetAsync(ctr, 0, 256, stream);

  // prep
  k_prep_phis<<<dim3(192), 256, 0, stream>>>(phi, sigma, phis);
  k_prep_all<<<dim3(4096), 256, 0, stream>>>(u, Mp, Mm, Mu, phis, X, W1, Wtoep);

  // GEMM1: projections; 128x256 tile, 512 threads, 1-D XCD-chunked grid
  {
    GB g{}; g.A = X; g.B = W1; g.A2T = A2T; g.Au = Au; g.zp = zpad;
    g.M = 2048; g.N = 26112;
    g2<0><<<dim3(1632), 512, 0, stream>>>(g);
  }
  // CONV: global Wtoep strips, locality-ordered XCD-chunked grid, splitK=8
  {
    GB g{}; g.A = Wtoep; g.B = A2T; g.Cb = partsBf; g.zp = zpad;
    g.M = 1024; g.N = 512;
    g2<1><<<dim3(1152), 256, 0, stream>>>(g);
  }
  k_combine<<<dim3(512), 256, 0, stream>>>(partsBf, Au, ybf);

  // companion-power stack Top[0..32] (+P at needed indices), then slots 33/34
  k_initTop<<<dim3(8192), 256, 0, stream>>>(my, Top, P);
  {
    const int cs[5] = {1, 2, 4, 8, 16};
    for (int li = 0; li < 5; ++li) {
      int c = cs[li];
      GB s{}; s.A = Top + 524288; s.Cb = Top + (size_t)(c + 1) * 524288;
      s.Pb = P; s.cidx = c; s.pthr = c - 2;
      s.zp = zpad; s.M = 512; s.N = 1024;
      g2<5><<<dim3(8, 4, c), 256, 0, stream>>>(s);
    }
    // slot33 = Top[31]*S^32 (=H63), slot34 = Top[32]*S^32 (=H64)
    GB s{}; s.A = Top + (size_t)31 * 524288;
    s.Cb = Top + (size_t)33 * 524288;
    s.Pb = P; s.cidx = 32; s.pthr = 99;
    s.zp = zpad; s.M = 512; s.N = 1024;
    g2<5><<<dim3(8, 4, 2), 256, 0, stream>>>(s);
  }

  // within-chunk solve: z = Tri(H) y; compact triangular grid, 16 slices
  {
    GB g{}; g.A = ybf; g.B = Top; g.Cf = zparts; g.zp = zpad;
    g.M = 2048; g.N = 512;
    g2<2><<<dim3(544), 256, 0, stream>>>(g);
  }
  k_zred<<<dim3(4096), 256, 0, stream>>>(zparts, zf, Wm, bnd, Abnd);

  // boundary chain: u_c precompute, then ONE fused 15-step chain kernel
  {
    GB g{}; g.A = Wm; g.B = Top; g.Cf = ubuf; g.zf = zf; g.zp = zpad;
    g.M = 64; g.N = 1024;
    g2<6><<<dim3(8, 1, 1), 256, 0, stream>>>(g);
  }
  k_chain<<<dim3(32), 256, 0, stream>>>(Top, ubuf, bnd, Abnd, ctr);
  {
    GB g{}; g.A = Abnd; g.B = Top; g.Cb = Abnd; g.zf = zf; g.zp = zpad;
    g.M = 32; g.N = 1024;
    g2<7><<<dim3(8, 1, 1), 256, 0, stream>>>(g);
  }

  // fixup: out = z + [H_{j+1}|G_j] @ Abnd
  {
    GB g{}; g.A = Abnd; g.B = Top; g.zf = zf; g.out = out; g.zp = zpad;
    g.M = 64; g.N = 16384;
    g2<3><<<dim3(128, 1, 1), 256, 0, stream>>>(g);
  }
}

// Round 16
// 710.837 us; speedup vs baseline: 1.0296x; 1.0296x over previous
//
#include <hip/hip_runtime.h>
#include <hip/hip_bf16.h>

// STU forward, R16: R14 base (15-launch chain reverted from R15's slow fused
// barrier) + 4-step chain unroll: S128 power, u128 precompute (V8), 7 serial
// k_bnd4 steps, mid-state batch fill (V9), odd fill (V7).
// Sizes: B=2, L=1024, K=24(x2), D=512, K_U=3, K_Y=2.

typedef unsigned short u16;
typedef __attribute__((ext_vector_type(8))) short  vshort8;
typedef __attribute__((ext_vector_type(4))) short  vshort4;
typedef __attribute__((ext_vector_type(4))) float  f32x4;
typedef __attribute__((ext_vector_type(4))) unsigned int vuint4;

__device__ __forceinline__ u16 f2b(float x) {
  __hip_bfloat16 h = __float2bfloat16(x);
  return __builtin_bit_cast(u16, h);
}
__device__ __forceinline__ float b2f(u16 x) {
  unsigned int u = ((unsigned int)x) << 16;
  return __builtin_bit_cast(float, u);
}

// async global->LDS, 16B per lane; LDS dest = wave-uniform base + lane*16
__device__ __forceinline__ void gll16(const u16* g, u16* l) {
  __builtin_amdgcn_global_load_lds((__attribute__((address_space(1))) void*)g,
                                   (__attribute__((address_space(3))) void*)l,
                                   16, 0, 0);
}

// A2T layout strides: [b:2][cj:8][kh:48][o:512][sp:128]
#define A2T_B  25165824
#define A2T_CJ 3145728
#define A2T_KH 65536

// ---------------------------------------------------------------------------
// Shared MFMA GEMM template. C[m,n] = sum_k A[m,k]*Bmat[n,k].
//  V0 GEMM1: 128x256 tile, 512 thr; A=X(2048x512) B=W1(26112x512); grid 1632
//  V1 CONV : A=Wtoep strip (d=bm-cj), B=A2T; 1-D grid 1152, splitK=8
//  V2 ZGEMM: A=gather(ybf), B=Top; 1-D grid 544 triangular, 16 slices
//  V3 FIXUP: A=Abnd(64x1024), B=Top[j+1] rows -> out = acc + zf
//  V5 SGEMM: A=Top[*], B=S^c^T from P; -> Top + P (dual-write)
//  V6 UGEMM: A=Wm, B=S32 rows -> ubuf=u64 f32 + Ubf bf16
//  V7 ODD  : A=Abnd even rows, B=S32 rows -> Abnd odd rows = acc + w_{2k}
//  V8 U128 : A=Ubf rows u64_{4k}, B=S64 rows -> ubuf2 = acc + u64_{4k+2}
//  V9 MID  : A=Abnd rows E_{4k}, B=S64 rows -> Abnd rows E_{4k+2}
// ---------------------------------------------------------------------------
struct GB {
  const u16* A; const u16* B;
  float* Cf; u16* Cb;
  const float* zf; float* out;
  u16* A2T; u16* Au;
  const u16* zp;
  u16* Pb; int cidx; int pthr;
  int M, N;
};

template<int V>
__global__ __launch_bounds__(V == 0 ? 512 : 256) void g2(GB a) {
  const int tid = threadIdx.x;
  int bn = blockIdx.x, bm = blockIdx.y;
  int zz = blockIdx.z;
  int cj = 0, cb = 0, cd = 0, slot = 0;
  int kbeg = 0, kend = 0;
  if (V == 0) {
    int f = blockIdx.x;
    int o = (f & 7) * 204 + (f >> 3);          // 1632 = 8 x 204
    bm = o & 15; bn = o >> 4; kend = 512;
  }
  if (V == 1) {
    int f = blockIdx.x;
    int o = (f & 7) * 144 + (f >> 3);          // 1152 = 8 x 144
    const int offs1[8] = {0, 256, 480, 672, 832, 960, 1056, 1120};
    cj = 0;
    if (o >= offs1[1]) cj = 1;
    if (o >= offs1[2]) cj = 2;
    if (o >= offs1[3]) cj = 3;
    if (o >= offs1[4]) cj = 4;
    if (o >= offs1[5]) cj = 5;
    if (o >= offs1[6]) cj = 6;
    if (o >= offs1[7]) cj = 7;
    int r = o - offs1[cj];
    int run = 8 - cj;
    int combo = r / run;                       // [0,32): (zzc, bn)
    bm = cj + (r - combo * run);
    int zzc = combo >> 2; bn = combo & 3;
    cb = zzc & 1; cd = bm - cj;
    slot = zzc * 8 + cj;
    kbeg = (zzc >> 1) * 1536; kend = kbeg + 1536;
  }
  if (V == 2) {
    int f = blockIdx.x;
    int o = (f & 7) * 68 + (f >> 3);           // 544 = 8 x 68
    const int offs2[16] = {0, 64, 124, 180, 232, 280, 324, 364,
                           400, 432, 460, 484, 504, 520, 532, 540};
    int s = 0;
#pragma unroll
    for (int c = 1; c < 16; ++c)
      if (o >= offs2[c]) s = c;
    int r = o - offs2[s];
    bm = s + (r >> 2); bn = r & 3;
    zz = s;
    kbeg = s * 1024; kend = kbeg + 1024;       // s<=bm guarantees validity
  }
  const int m0 = bm * 128;
  const int n0 = (V == 0) ? bn * 256 : bn * 128;
  if (V == 3 || V == 5 || V == 6 || V == 7 || V == 8 || V == 9) kend = 1024;

  __shared__ u16 smem[V == 0 ? 24576 : 16384];
  f32x4 acc[4][4];
#pragma unroll
  for (int i = 0; i < 4; i++)
#pragma unroll
    for (int j = 0; j < 4; j++) acc[i][j] = f32x4{0.f, 0.f, 0.f, 0.f};

  const int lane = tid & 63, wv = tid >> 6;
  const int wr = (V == 0) ? (wv >> 2) : (wv >> 1);
  const int wc = (V == 0) ? (wv & 3) : (wv & 1);
  const u16* Ap = a.A;
  if (V == 5) Ap = a.A + (size_t)zz * 524288;
  const u16* zpl = a.zp + lane * 8;

  auto gaddrA = [&](int it, int k0) -> const u16* {
    int lrow = (it * 4 + wv) * 16 + (lane & 15);
    int kk = k0 + ((lane >> 4) << 3);
    if (V == 1) return Ap + (size_t)cd * 786432 + (size_t)lrow * 6144 + kk;
    if (V == 2) {
      int m = m0 + lrow, j = m >> 6, b = (m >> 5) & 1, c = m & 31;
      int tau = kk >> 9, p = kk & 511;
      if (tau > j) return zpl;
      return Ap + (size_t)(b * 1024 + c * 32 + j - tau) * 512 + p;
    }
    if (V == 3) { int m = m0 + lrow; return (m < a.M) ? Ap + (size_t)m * 1024 + kk : zpl; }
    if (V == 5) return Ap + (size_t)(m0 + lrow) * 1024 + kk;
    if (V == 6) return (lrow < 64) ? Ap + (size_t)lrow * 1024 + kk : zpl;
    if (V == 7) {
      if (lrow < 32) {
        int b = lrow & 1, k2 = lrow >> 1;
        return Ap + (size_t)(b * 32 + 2 * k2) * 1024 + kk;
      }
      return zpl;
    }
    if (V == 8) {
      if (lrow < 14) {
        int b = lrow & 1, k = lrow >> 1;
        return Ap + (size_t)((8 * k) | b) * 1024 + kk;   // Ubf row of u64_{4k}
      }
      return zpl;
    }
    // V9
    if (lrow < 16) {
      int b = lrow & 1, k = lrow >> 1;
      return Ap + (size_t)(b * 32 + 4 * k) * 1024 + kk;  // Abnd row E_{4k}
    }
    return zpl;
  };
  auto gaddrB = [&](int it, int k0) -> const u16* {
    int lrow = (it * 4 + wv) * 16 + (lane & 15);
    int kk = k0 + ((lane >> 4) << 3);
    int n = n0 + lrow;
    if (V == 1) {
      int kh = kk >> 7, sp = kk & 127;
      return a.B + (size_t)cb * A2T_B + (size_t)cj * A2T_CJ
           + (size_t)kh * A2T_KH + (size_t)n * 128 + sp;
    }
    if (V == 2) {
      int tau = kk >> 9, p = kk & 511;
      return a.B + (size_t)tau * 524288 + (size_t)n * 1024 + p;
    }
    if (V == 3) {
      int jn = n >> 9, o = n & 511;
      return a.B + (size_t)(jn + 1) * 524288 + (size_t)o * 1024 + kk;
    }
    if (V == 5) {
      // B[n][kk] = S^c^T[n][kk] from P
      return (kk < 512)
          ? a.Pb + (size_t)a.cidx * 524288 + (size_t)n * 512 + kk
          : a.Pb + (size_t)(a.cidx - 1) * 524288 + (size_t)n * 512 + (kk - 512);
    }
    if (V == 8 || V == 9) {
      // rows of S64 = [Top34 ; Top33]
      return (n < 512)
          ? a.B + (size_t)34 * 524288 + (size_t)n * 1024 + kk
          : a.B + (size_t)33 * 524288 + (size_t)(n - 512) * 1024 + kk;
    }
    // V6/V7: rows of S32 = [Top32 ; Top31]
    return (n < 512)
        ? a.B + (size_t)32 * 524288 + (size_t)n * 1024 + kk
        : a.B + (size_t)31 * 524288 + (size_t)(n - 512) * 1024 + kk;
  };

  auto stage = [&](int c, int k0) {
    if (V == 0) {
      int kk = k0 + ((lane >> 4) << 3);
      int lrowA = wv * 16 + (lane & 15);
      gll16(Ap + (size_t)(m0 + lrowA) * 512 + kk, smem + c * 4096 + wv * 512);
#pragma unroll
      for (int it = 0; it < 2; ++it) {
        int lrowB = (it * 8 + wv) * 16 + (lane & 15);
        gll16(a.B + (size_t)(n0 + lrowB) * 512 + kk,
              smem + 8192 + c * 8192 + (it * 8 + wv) * 512);
      }
    } else {
#pragma unroll
      for (int it = 0; it < 2; ++it) {
        int weff = wv + it * 4;
        gll16(gaddrA(it, k0), smem + c * 4096 + weff * 512);
        gll16(gaddrB(it, k0), smem + 8192 + c * 4096 + weff * 512);
      }
    }
  };

  if (kbeg < kend) stage(0, kbeg);
  __syncthreads();                 // drains the prologue stage
  int cur = 0;
  for (int k0 = kbeg; k0 < kend; k0 += 32) {
    if (k0 + 32 < kend) stage(cur ^ 1, k0 + 32);   // async prefetch next tile
    vshort8 af[4], bf_[4];
#pragma unroll
    for (int s = 0; s < 4; s++) {
      af[s] = *(const vshort8*)&smem[cur * 4096 +
                (((wr * 4 + s) * 4 + (lane >> 4)) * 16 + (lane & 15)) * 8];
      if (V == 0)
        bf_[s] = *(const vshort8*)&smem[8192 + cur * 8192 +
                  (((wc * 4 + s) * 4 + (lane >> 4)) * 16 + (lane & 15)) * 8];
      else
        bf_[s] = *(const vshort8*)&smem[8192 + cur * 4096 +
                  (((wc * 4 + s) * 4 + (lane >> 4)) * 16 + (lane & 15)) * 8];
    }
#pragma unroll
    for (int i = 0; i < 4; i++)
#pragma unroll
      for (int j = 0; j < 4; j++)
        acc[i][j] = __builtin_amdgcn_mfma_f32_16x16x32_bf16(af[i], bf_[j], acc[i][j], 0, 0, 0);
    __syncthreads();               // drains prefetch + protects buffer swap
    cur ^= 1;
  }

  // ---- epilogue ----
  if (V == 0 && bn < 96) {
    // 4 phases; phase p handles n-cols [n0+p*64, +64) via LDS transpose.
    const int strd = 136;
    const int b = m0 >> 10;
    const int cjw = (m0 & 1023) >> 7;
#pragma unroll
    for (int p = 0; p < 4; ++p) {
      __syncthreads();
      if (wc == p) {
#pragma unroll
        for (int i = 0; i < 4; i++) {
#pragma unroll
          for (int j = 0; j < 4; j++) {
            f32x4 v = acc[i][j];
            int mloc = wr * 64 + i * 16 + ((lane >> 4) << 2);  // sp in [0,128)
            int phys = j * 16 + (lane & 15);                   // n-off in [0,64)
            vshort4 pk = { (short)f2b(v[0]), (short)f2b(v[1]),
                           (short)f2b(v[2]), (short)f2b(v[3]) };
            *(vshort4*)&smem[phys * strd + mloc] = pk;
          }
        }
      }
      __syncthreads();
      int rowp = tid >> 3, t8 = tid & 7;
      int n = n0 + p * 64 + rowp;
      int o = n & 511, kh = n >> 9;
      u16* dst = a.A2T + (size_t)b * A2T_B + (size_t)cjw * A2T_CJ
               + (size_t)kh * A2T_KH + (size_t)o * 128 + t8 * 16;
      const u16* srcl = &smem[rowp * strd + t8 * 16];
      *(vuint4*)(dst)     = *(const vuint4*)(srcl);
      *(vuint4*)(dst + 8) = *(const vuint4*)(srcl + 8);
    }
    return;
  }

#pragma unroll
  for (int i = 0; i < 4; i++) {
    int em = m0 + wr * 64 + i * 16 + ((lane >> 4) << 2);
#pragma unroll
    for (int j = 0; j < 4; j++) {
      int n = n0 + wc * 64 + j * 16 + (lane & 15);
      f32x4 v = acc[i][j];
      if (V == 0) {
        int b = em >> 10, s = em & 1023;
        int jj = (n - 24576) >> 9, o = n & 511;
#pragma unroll
        for (int t = 0; t < 4; t++)
          a.Au[((size_t)(b * 3 + jj) * 1024 + (s + t)) * 512 + o] = f2b(v[t]);
      } else if (V == 1) {
        u16* C = a.Cb + (size_t)slot * 524288;
#pragma unroll
        for (int t = 0; t < 4; t++) C[(size_t)(em + t) * 512 + n] = f2b(v[t]);
      } else if (V == 2) {
        float* C = a.Cf + (size_t)zz * 1048576;
#pragma unroll
        for (int t = 0; t < 4; t++) C[(size_t)(em + t) * 512 + n] = v[t];
      } else if (V == 3) {
        int jj = n >> 9, oo = n & 511;
#pragma unroll
        for (int t = 0; t < 4; t++) {
          int m = em + t;
          if (m < a.M) {
            int b = m >> 5, c = m & 31;
            float zv = a.zf[(size_t)(jj * 64 + b * 32 + c) * 512 + oo];
            a.out[(size_t)b * 524288 + (size_t)(c * 32 + jj) * 512 + oo] = v[t] + zv;
          }
        }
      } else if (V == 5) {
        u16* C = a.Cb + (size_t)zz * 524288;
#pragma unroll
        for (int t = 0; t < 4; t++) C[(size_t)(em + t) * 1024 + n] = f2b(v[t]);
      } else if (V == 6) {
        int jrow = (n < 512) ? 31 : 30, oo = n & 511;
#pragma unroll
        for (int t = 0; t < 4; t++) {
          int m = em + t;
          if (m < 62) {
            int b = m & 1, c = m >> 1;
            float val = v[t] + a.zf[(size_t)(jrow * 64 + b * 32 + (c + 1)) * 512 + oo];
            a.Cf[(size_t)m * 1024 + n] = val;
            a.Cb[(size_t)m * 1024 + n] = f2b(val);   // bf16 copy for V8
          }
        }
      } else if (V == 7) {
        int jrow = (n < 512) ? 31 : 30, oo = n & 511;
#pragma unroll
        for (int t = 0; t < 4; t++) {
          int m = em + t;
          if (m < 32) {
            int b = m & 1, k2 = m >> 1;
            float val = v[t] + a.zf[(size_t)(jrow * 64 + b * 32 + 2 * k2) * 512 + oo];
            a.Cb[(size_t)(b * 32 + 2 * k2 + 1) * 1024 + n] = f2b(val);
          }
        }
      } else if (V == 8) {
        // u128_{4k} = acc + u64_{4k+2}; rows m=(k<<1)|b, k<7
#pragma unroll
        for (int t = 0; t < 4; t++) {
          int m = em + t;
          if (m < 14) {
            int b = m & 1, k = m >> 1;
            a.Cf[(size_t)m * 1024 + n] =
                v[t] + a.zf[(size_t)((8 * k + 4) | b) * 1024 + n];
          }
        }
      } else { // V9: E_{4k+2} = acc + u64_{4k}; rows m=(k<<1)|b, k<8
#pragma unroll
        for (int t = 0; t < 4; t++) {
          int m = em + t;
          if (m < 16) {
            int b = m & 1, k = m >> 1;
            float val = v[t] + a.zf[(size_t)((8 * k) | b) * 1024 + n];
            a.Cb[(size_t)(b * 32 + 4 * k + 2) * 1024 + n] = f2b(val);
          }
        }
      }
    }
  }

  // V5 dual-write: P[c+1+zz][n][m] = C[m][n] via LDS transpose (2 passes)
  if (V == 5) {
    if (zz >= a.pthr) {
      const int strd = 136;
      u16* Pout = a.Pb + (size_t)(a.cidx + 1 + zz) * 524288;
#pragma unroll
      for (int p = 0; p < 2; ++p) {
        __syncthreads();
        if (wc == p) {
#pragma unroll
          for (int i = 0; i < 4; i++) {
#pragma unroll
            for (int j = 0; j < 4; j++) {
              f32x4 v = acc[i][j];
              int mloc = wr * 64 + i * 16 + ((lane >> 4) << 2);  // m-off [0,128)
              int phys = j * 16 + (lane & 15);                   // n-off [0,64)
              vshort4 pk = { (short)f2b(v[0]), (short)f2b(v[1]),
                             (short)f2b(v[2]), (short)f2b(v[3]) };
              *(vshort4*)&smem[phys * strd + mloc] = pk;
            }
          }
        }
        __syncthreads();
        int rowp = tid >> 2, t4 = tid & 3;
        u16* dst = Pout + (size_t)(n0 + p * 64 + rowp) * 512 + m0 + t4 * 32;
        const u16* srcl = &smem[rowp * strd + t4 * 32];
#pragma unroll
        for (int q = 0; q < 4; ++q)
          *(vuint4*)(dst + q * 8) = *(const vuint4*)(srcl + q * 8);
      }
    }
  }
}

// ---------------------------------------------------------------------------
// prep / glue kernels
// ---------------------------------------------------------------------------
// phis[tau*48 + kf]: kf<24 -> phi_s[tau,kf]; kf>=24 -> phi_s[tau,kf-24]*(-1)^tau
__global__ void k_prep_phis(const float* __restrict__ phi, const float* __restrict__ sigma,
                            float* __restrict__ phis) {
  int i = blockIdx.x * 256 + threadIdx.x;
  if (i >= 1024 * 48) return;
  int tau = i / 48, kf = i % 48, k = (kf >= 24) ? kf - 24 : kf;
  float v = phi[tau * 24 + k] * powf(sigma[k], 0.25f);
  if (kf >= 24 && (tau & 1)) v = -v;
  phis[i] = v;
}

// fused: X convert (vec4), W1 convert (vec4 x4 rounds), Wtoep build (vec8)
__global__ void k_prep_all(const float* __restrict__ u, const float* __restrict__ Mp,
                           const float* __restrict__ Mm, const float* __restrict__ Mu,
                           const float* __restrict__ phis,
                           u16* __restrict__ X, u16* __restrict__ W1,
                           u16* __restrict__ Wtoep) {
  int gid = blockIdx.x * 256 + threadIdx.x;   // [0, 1048576)
  if (gid < 262144) {
    int i4 = gid * 4;
    f32x4 v = *(const f32x4*)(u + i4);
    vshort4 pk = { (short)f2b(v[0]), (short)f2b(v[1]), (short)f2b(v[2]), (short)f2b(v[3]) };
    *(vshort4*)(X + i4) = pk;
  }
#pragma unroll
  for (int r = 0; r < 4; ++r) {
    int item = gid + r * 1048576;
    if (item < 3342336) {
      int i4 = item * 4;
      const float* src; int off;
      if (i4 < 6291456) { src = Mp; off = i4; }
      else if (i4 < 12582912) { src = Mm; off = i4 - 6291456; }
      else { src = Mu; off = i4 - 12582912; }
      f32x4 v = *(const f32x4*)(src + off);
      vshort4 pk = { (short)f2b(v[0]), (short)f2b(v[1]), (short)f2b(v[2]), (short)f2b(v[3]) };
      *(vshort4*)(W1 + i4) = pk;
    }
  }
  if (gid < 786432) {
    int i = gid * 8;
    int kap = i % 6144, row = i / 6144;
    int tp = row & 127, d = row >> 7;
    int kh = kap >> 7, sp = kap & 127;
    int tau0 = d * 128 + tp - sp;
    u16 vals[8];
#pragma unroll
    for (int e = 0; e < 8; ++e) {
      int tau = tau0 - e;
      vals[e] = (tau >= 0 && tau < 1024) ? f2b(phis[tau * 48 + kh]) : (u16)0;
    }
    *(vuint4*)(Wtoep + i) = *(const vuint4*)vals;
  }
}

// Top[0]=[I|0], Top[1]=[M1|M2]; P[0]=Top[0]^T, P[1]=Top[1]^T
__global__ void k_initTop(const float* __restrict__ my, u16* __restrict__ Top,
                          u16* __restrict__ P) {
  int i = blockIdx.x * 256 + threadIdx.x;
  if (i >= 2097152) return;
  if (i < 1048576) {
    int mat = i >> 19, rem = i & 524287, o = rem >> 10, k = rem & 1023;
    u16 v;
    if (mat == 0) v = (k == o) ? (u16)0x3F80 : (u16)0;
    else v = (k < 512) ? f2b(my[o * 512 + k]) : f2b(my[262144 + o * 512 + (k - 512)]);
    Top[i] = v;
  } else {
    int j = i - 1048576;
    int mat = j >> 19, rem = j & 524287, n = rem >> 9, m = rem & 511;
    u16 v;
    if (mat == 0) v = (n == m) ? (u16)0x3F80 : (u16)0;
    else v = (n < 512) ? f2b(my[m * 512 + n]) : f2b(my[262144 + m * 512 + (n - 512)]);
    P[(size_t)mat * 524288 + (size_t)n * 512 + m] = v;
  }
}

__device__ __forceinline__ void addp(float* acc, vuint4 v) {
  const unsigned int* vu = (const unsigned int*)&v;
#pragma unroll
  for (int e = 0; e < 4; ++e) {
    unsigned int pw = vu[e];
    acc[2 * e]     += __builtin_bit_cast(float, (pw & 0xffffu) << 16);
    acc[2 * e + 1] += __builtin_bit_cast(float, pw & 0xffff0000u);
  }
}

// ybf[b,t,og*8..] = sum_j Au[b,j,t-j,:] + (t>=2 ? valid bf16 conv partials : 0)
__global__ void k_combine(const u16* __restrict__ parts, const u16* __restrict__ Au,
                          u16* __restrict__ ybf) {
  int i = blockIdx.x * 256 + threadIdx.x;
  if (i >= 131072) return;
  int og = i & 63, t = (i >> 6) & 1023, b = i >> 16;
  float acc[8];
#pragma unroll
  for (int e = 0; e < 8; ++e) acc[e] = 0.f;
#pragma unroll
  for (int j = 0; j < 3; j++)
    if (t >= j)
      addp(acc, *(const vuint4*)(Au + ((size_t)(b * 3 + j) * 1024 + (t - j)) * 512 + og * 8));
  if (t >= 2) {
    int tp = t - 2, bmv = tp >> 7;
#pragma unroll
    for (int g = 0; g < 8; ++g) {
      if ((g & 1) != b) continue;
      const u16* base = parts + (size_t)(g * 8) * 524288 + (size_t)tp * 512 + og * 8;
      for (int j = 0; j <= bmv; ++j)
        addp(acc, *(const vuint4*)(base + (size_t)j * 524288));
    }
  }
  u16 o16[8];
#pragma unroll
  for (int e = 0; e < 8; ++e) o16[e] = f2b(acc[e]);
  *(vuint4*)(ybf + ((size_t)(b * 1024 + t)) * 512 + og * 8) = *(vuint4*)o16;
}

// fused: zf reduce + Wm extraction + bnd/Abnd zero-init
__global__ void k_zred(const float* __restrict__ zp, float* __restrict__ z,
                       u16* __restrict__ Wm, float* __restrict__ bnd,
                       u16* __restrict__ Abnd) {
  int i = blockIdx.x * 256 + threadIdx.x;
  if (i < 2048) bnd[i] = 0.f;
  if (i < 1024) { Abnd[i] = 0; Abnd[32768 + i] = 0; }
  if (i >= 1048576) return;
  int nsum = (i >> 16) + 1;        // bm = i>>16 in [0,16)
  float s = 0.f;
  for (int j = 0; j < nsum; ++j) s += zp[(size_t)j * 1048576 + i];
  z[i] = s;
  int m = i >> 9, jj = m >> 6, rem = m & 63, b = rem >> 5, c = rem & 31, oo = i & 511;
  if (jj == 31) Wm[(size_t)((c << 1) | b) * 1024 + oo] = f2b(s);
  if (jj == 30) Wm[(size_t)((c << 1) | b) * 1024 + 512 + oo] = f2b(s);
}

// quad chain step k: E_{4k+4} = S128 E_{4k} + u128_{4k}; S128 rows slots 36/35
__global__ __launch_bounds__(256) void k_bnd4(const u16* __restrict__ Top,
                                              const float* __restrict__ ubuf2,
                                              float* __restrict__ bnd,
                                              u16* __restrict__ Abnd, int k) {
  __shared__ float st[2048];
  int tid = threadIdx.x;
  const float* s0 = bnd + (size_t)k * 2048;
  for (int j = tid; j < 2048; j += 256) st[j] = s0[j];
  __syncthreads();
  int q4 = blockIdx.x * 256 + tid;  // [0,8192)
  int q = q4 >> 2, quarter = q4 & 3;
  int b = q >> 10, kk = q & 1023;
  const u16* row = (kk < 512) ? Top + (size_t)36 * 524288 + (size_t)kk * 1024
                              : Top + (size_t)35 * 524288 + (size_t)(kk - 512) * 1024;
  const float* stb = st + b * 1024 + quarter * 256;
  const u16* rp = row + quarter * 256;
  float sum = 0.f;
  for (int t = 0; t < 32; ++t) {
    vuint4 v = *(const vuint4*)(rp + t * 8);
    const unsigned int* vu = (const unsigned int*)&v;
#pragma unroll
    for (int e = 0; e < 4; ++e) {
      unsigned int pw = vu[e];
      float lo = __builtin_bit_cast(float, (pw & 0xffffu) << 16);
      float hi = __builtin_bit_cast(float, pw & 0xffff0000u);
      sum += lo * stb[t * 8 + e * 2] + hi * stb[t * 8 + e * 2 + 1];
    }
  }
  sum += __shfl_xor(sum, 1);
  sum += __shfl_xor(sum, 2);
  if (quarter == 0) {
    float s = sum + ubuf2[(size_t)((k << 1) | b) * 1024 + kk];
    bnd[(size_t)(k + 1) * 2048 + b * 1024 + kk] = s;
    Abnd[(size_t)(b * 32 + 4 * k + 4) * 1024 + kk] = f2b(s);
  }
}

// ---------------------------------------------------------------------------
extern "C" void kernel_launch(void* const* d_in, const int* in_sizes, int n_in,
                              void* d_out, int out_size, void* d_ws, size_t ws_size,
                              hipStream_t stream) {
  const float* u     = (const float*)d_in[0];
  const float* Mu    = (const float*)d_in[1];
  const float* Mp    = (const float*)d_in[2];
  const float* Mm    = (const float*)d_in[3];
  const float* my    = (const float*)d_in[4];
  const float* sigma = (const float*)d_in[5];
  const float* phi   = (const float*)d_in[6];
  float* out = (float*)d_out;

  char* ws = (char*)d_ws;
  size_t off = 0;
  auto alc = [&](size_t b) { size_t p = off; off = (off + b + 255) & ~(size_t)255; return p; };
  u16*  X     = (u16*)(ws + alc(2097152));
  u16*  Wtoep = (u16*)(ws + alc(12582912));    // 8 d x 128 x 6144
  u16*  A2T   = (u16*)(ws + alc(100663296));   // [b][cj][kh][o][sp]
  u16*  Au    = (u16*)(ws + alc(6291456));
  u16*  W1    = (u16*)(ws + alc(26738688));    // 26112x512; parts region spans W1+tail
  char* ptail = ws + alc(40370176); (void)ptail; // W1+tail = 64 MiB exactly
  float* phis = (float*)(ws + alc(196608));    // [1024 tau][48 kf] f32
  float* bnd  = (float*)(ws + alc(131072));    // chain states x 2048 f32
  u16*  Abnd  = (u16*)(ws + alc(131072));      // 64 x 1024 bf16 boundary states
  u16*  Wm    = (u16*)(ws + alc(131072));      // 64 x 1024 bf16 w_c
  float* ubuf = (float*)(ws + alc(262144));    // 64 x 1024 f32 u64
  u16*  Ubf   = (u16*)(ws + alc(131072));      // 64 x 1024 bf16 u64
  float* ubuf2 = (float*)(ws + alc(65536));    // 16 x 1024 f32 u128
  u16*  zpad  = (u16*)(ws + alc(32768));       // zero page for predicated lanes
  if (off > ws_size) return;
  // lifetime-disjoint aliases:
  u16*  partsBf = (u16*)W1;                    // 64 conv slots x [1024][512] bf16 = 64 MiB
  float* zparts = (float*)W1;                  // 16 zgemm slots x 4 MiB f32 = 64 MiB
  u16*  ybf = A2T;                             // 2 MiB (after conv)
  float* zf = (float*)((char*)A2T + (4 << 20));
  u16*  Top = (u16*)((char*)A2T + (size_t)(8 << 20));   // 37 slots (0..32,33/34=H63/64,35/36=H127/128)
  u16*  P   = (u16*)((char*)A2T + (size_t)(46 << 20));  // 35 slots (Top^T)

  hipMemsetAsync(zpad, 0, 32768, stream);

  // prep
  k_prep_phis<<<dim3(192), 256, 0, stream>>>(phi, sigma, phis);
  k_prep_all<<<dim3(4096), 256, 0, stream>>>(u, Mp, Mm, Mu, phis, X, W1, Wtoep);

  // GEMM1: projections; 128x256 tile, 512 threads, 1-D XCD-chunked grid
  {
    GB g{}; g.A = X; g.B = W1; g.A2T = A2T; g.Au = Au; g.zp = zpad;
    g.M = 2048; g.N = 26112;
    g2<0><<<dim3(1632), 512, 0, stream>>>(g);
  }
  // CONV: global Wtoep strips, locality-ordered XCD-chunked grid, splitK=8
  {
    GB g{}; g.A = Wtoep; g.B = A2T; g.Cb = partsBf; g.zp = zpad;
    g.M = 1024; g.N = 512;
    g2<1><<<dim3(1152), 256, 0, stream>>>(g);
  }
  k_combine<<<dim3(512), 256, 0, stream>>>(partsBf, Au, ybf);

  // companion-power stack Top[0..32] (+P), slots 33/34 (H63/H64, +P), 35/36 (H127/H128)
  k_initTop<<<dim3(8192), 256, 0, stream>>>(my, Top, P);
  {
    const int cs[5] = {1, 2, 4, 8, 16};
    for (int li = 0; li < 5; ++li) {
      int c = cs[li];
      GB s{}; s.A = Top + 524288; s.Cb = Top + (size_t)(c + 1) * 524288;
      s.Pb = P; s.cidx = c; s.pthr = c - 2;
      s.zp = zpad; s.M = 512; s.N = 1024;
      g2<5><<<dim3(8, 4, c), 256, 0, stream>>>(s);
    }
    // slot33 = Top[31]*S^32 (=H63), slot34 = Top[32]*S^32 (=H64); also P[33],P[34]
    GB s{}; s.A = Top + (size_t)31 * 524288;
    s.Cb = Top + (size_t)33 * 524288;
    s.Pb = P; s.cidx = 32; s.pthr = 0;
    s.zp = zpad; s.M = 512; s.N = 1024;
    g2<5><<<dim3(8, 4, 2), 256, 0, stream>>>(s);
    // slot35 = Top[33]*S^64 (=H127), slot36 = Top[34]*S^64 (=H128)
    GB t{}; t.A = Top + (size_t)33 * 524288;
    t.Cb = Top + (size_t)35 * 524288;
    t.Pb = P; t.cidx = 34; t.pthr = 99;
    t.zp = zpad; t.M = 512; t.N = 1024;
    g2<5><<<dim3(8, 4, 2), 256, 0, stream>>>(t);
  }

  // within-chunk solve: z = Tri(H) y; compact triangular grid, 16 slices
  {
    GB g{}; g.A = ybf; g.B = Top; g.Cf = zparts; g.zp = zpad;
    g.M = 2048; g.N = 512;
    g2<2><<<dim3(544), 256, 0, stream>>>(g);
  }
  k_zred<<<dim3(4096), 256, 0, stream>>>(zparts, zf, Wm, bnd, Abnd);

  // u64 = S32 w + w_next (f32 + bf16 copies)
  {
    GB g{}; g.A = Wm; g.B = Top; g.Cf = ubuf; g.Cb = Ubf; g.zf = zf; g.zp = zpad;
    g.M = 64; g.N = 1024;
    g2<6><<<dim3(8, 1, 1), 256, 0, stream>>>(g);
  }
  // u128_{4k} = S64 u64_{4k} + u64_{4k+2}
  {
    GB g{}; g.A = Ubf; g.B = Top; g.Cf = ubuf2; g.zf = ubuf; g.zp = zpad;
    g.M = 16; g.N = 1024;
    g2<8><<<dim3(8, 1, 1), 256, 0, stream>>>(g);
  }
  // 7 serial quad-steps: E_4..E_28
  for (int k = 0; k < 7; ++k)
    k_bnd4<<<dim3(32), 256, 0, stream>>>(Top, ubuf2, bnd, Abnd, k);
  // mid fill: E_{4k+2} = S64 E_{4k} + u64_{4k}
  {
    GB g{}; g.A = Abnd; g.B = Top; g.Cb = Abnd; g.zf = ubuf; g.zp = zpad;
    g.M = 16; g.N = 1024;
    g2<9><<<dim3(8, 1, 1), 256, 0, stream>>>(g);
  }
  // odd fill: E_{2k+1} = S32 E_{2k} + w_{2k}
  {
    GB g{}; g.A = Abnd; g.B = Top; g.Cb = Abnd; g.zf = zf; g.zp = zpad;
    g.M = 32; g.N = 1024;
    g2<7><<<dim3(8, 1, 1), 256, 0, stream>>>(g);
  }

  // fixup: out = z + [H_{j+1}|G_j] @ Abnd
  {
    GB g{}; g.A = Abnd; g.B = Top; g.zf = zf; g.out = out; g.zp = zpad;
    g.M = 64; g.N = 16384;
    g2<3><<<dim3(128, 1, 1), 256, 0, stream>>>(g);
  }
}

// Round 17
// 692.678 us; speedup vs baseline: 1.0566x; 1.0262x over previous
//
#include <hip/hip_runtime.h>
#include <hip/hip_bf16.h>

// STU forward, R17: exact revert to R14 (best measured: 693 us).
// R15 (fused barrier chain) and R16 (4-step unroll) both regressed; the
// 15-launch chain is the measured optimum for the serial part.
// Sizes: B=2, L=1024, K=24(x2), D=512, K_U=3, K_Y=2.

typedef unsigned short u16;
typedef __attribute__((ext_vector_type(8))) short  vshort8;
typedef __attribute__((ext_vector_type(4))) short  vshort4;
typedef __attribute__((ext_vector_type(4))) float  f32x4;
typedef __attribute__((ext_vector_type(4))) unsigned int vuint4;

__device__ __forceinline__ u16 f2b(float x) {
  __hip_bfloat16 h = __float2bfloat16(x);
  return __builtin_bit_cast(u16, h);
}
__device__ __forceinline__ float b2f(u16 x) {
  unsigned int u = ((unsigned int)x) << 16;
  return __builtin_bit_cast(float, u);
}

// async global->LDS, 16B per lane; LDS dest = wave-uniform base + lane*16
__device__ __forceinline__ void gll16(const u16* g, u16* l) {
  __builtin_amdgcn_global_load_lds((__attribute__((address_space(1))) void*)g,
                                   (__attribute__((address_space(3))) void*)l,
                                   16, 0, 0);
}

// A2T layout strides: [b:2][cj:8][kh:48][o:512][sp:128]
#define A2T_B  25165824
#define A2T_CJ 3145728
#define A2T_KH 65536

// ---------------------------------------------------------------------------
// Shared MFMA GEMM template. C[m,n] = sum_k A[m,k]*Bmat[n,k].
//  V0 GEMM1: 128x256 tile, 512 thr; A=X(2048x512) B=W1(26112x512); grid 1632
//  V1 CONV : A=Wtoep strip (d=bm-cj), B=A2T; 1-D grid 1152, splitK=8
//  V2 ZGEMM: A=gather(ybf), B=Top; 1-D grid 544 triangular, 16 slices
//  V3 FIXUP: A=Abnd(64x1024), B=Top[j+1] rows -> out = acc + zf
//  V5 SGEMM: A=Top[1+bz], B=S^c^T from P; -> Top[c+1+bz] + P[c+1+bz] (dual)
//  V6 UGEMM: A=Wm(64x1024), B=S32 rows -> ubuf = acc + w_{c+1} (f32)
//  V7 ODD  : A=Abnd even rows, B=S32 rows -> Abnd odd rows = acc + w_{2k}
// ---------------------------------------------------------------------------
struct GB {
  const u16* A; const u16* B;
  float* Cf; u16* Cb;
  const float* zf; float* out;
  u16* A2T; u16* Au;
  const u16* zp;
  u16* Pb; int cidx; int pthr;
  int M, N;
};

template<int V>
__global__ __launch_bounds__(V == 0 ? 512 : 256) void g2(GB a) {
  const int tid = threadIdx.x;
  int bn = blockIdx.x, bm = blockIdx.y;
  int zz = blockIdx.z;
  int cj = 0, cb = 0, cd = 0, slot = 0;
  int kbeg = 0, kend = 0;
  if (V == 0) {
    int f = blockIdx.x;
    int o = (f & 7) * 204 + (f >> 3);          // 1632 = 8 x 204
    bm = o & 15; bn = o >> 4; kend = 512;
  }
  if (V == 1) {
    int f = blockIdx.x;
    int o = (f & 7) * 144 + (f >> 3);          // 1152 = 8 x 144
    const int offs1[8] = {0, 256, 480, 672, 832, 960, 1056, 1120};
    cj = 0;
    if (o >= offs1[1]) cj = 1;
    if (o >= offs1[2]) cj = 2;
    if (o >= offs1[3]) cj = 3;
    if (o >= offs1[4]) cj = 4;
    if (o >= offs1[5]) cj = 5;
    if (o >= offs1[6]) cj = 6;
    if (o >= offs1[7]) cj = 7;
    int r = o - offs1[cj];
    int run = 8 - cj;
    int combo = r / run;                       // [0,32): (zzc, bn)
    bm = cj + (r - combo * run);
    int zzc = combo >> 2; bn = combo & 3;
    cb = zzc & 1; cd = bm - cj;
    slot = zzc * 8 + cj;
    kbeg = (zzc >> 1) * 1536; kend = kbeg + 1536;
  }
  if (V == 2) {
    int f = blockIdx.x;
    int o = (f & 7) * 68 + (f >> 3);           // 544 = 8 x 68
    const int offs2[16] = {0, 64, 124, 180, 232, 280, 324, 364,
                           400, 432, 460, 484, 504, 520, 532, 540};
    int s = 0;
#pragma unroll
    for (int c = 1; c < 16; ++c)
      if (o >= offs2[c]) s = c;
    int r = o - offs2[s];
    bm = s + (r >> 2); bn = r & 3;
    zz = s;
    kbeg = s * 1024; kend = kbeg + 1024;       // s<=bm guarantees validity
  }
  const int m0 = bm * 128;
  const int n0 = (V == 0) ? bn * 256 : bn * 128;
  if (V == 3 || V == 5 || V == 6 || V == 7) kend = 1024;

  __shared__ u16 smem[V == 0 ? 24576 : 16384];
  f32x4 acc[4][4];
#pragma unroll
  for (int i = 0; i < 4; i++)
#pragma unroll
    for (int j = 0; j < 4; j++) acc[i][j] = f32x4{0.f, 0.f, 0.f, 0.f};

  const int lane = tid & 63, wv = tid >> 6;
  const int wr = (V == 0) ? (wv >> 2) : (wv >> 1);
  const int wc = (V == 0) ? (wv & 3) : (wv & 1);
  const u16* Ap = a.A;
  if (V == 5) Ap = a.A + (size_t)zz * 524288;
  const u16* zpl = a.zp + lane * 8;

  auto gaddrA = [&](int it, int k0) -> const u16* {
    int lrow = (it * 4 + wv) * 16 + (lane & 15);
    int kk = k0 + ((lane >> 4) << 3);
    if (V == 1) return Ap + (size_t)cd * 786432 + (size_t)lrow * 6144 + kk;
    if (V == 2) {
      int m = m0 + lrow, j = m >> 6, b = (m >> 5) & 1, c = m & 31;
      int tau = kk >> 9, p = kk & 511;
      if (tau > j) return zpl;
      return Ap + (size_t)(b * 1024 + c * 32 + j - tau) * 512 + p;
    }
    if (V == 3) { int m = m0 + lrow; return (m < a.M) ? Ap + (size_t)m * 1024 + kk : zpl; }
    if (V == 5) return Ap + (size_t)(m0 + lrow) * 1024 + kk;
    if (V == 6) return (lrow < 64) ? Ap + (size_t)lrow * 1024 + kk : zpl;
    // V7
    if (lrow < 32) {
      int b = lrow & 1, k2 = lrow >> 1;
      return Ap + (size_t)(b * 32 + 2 * k2) * 1024 + kk;
    }
    return zpl;
  };
  auto gaddrB = [&](int it, int k0) -> const u16* {
    int lrow = (it * 4 + wv) * 16 + (lane & 15);
    int kk = k0 + ((lane >> 4) << 3);
    int n = n0 + lrow;
    if (V == 1) {
      int kh = kk >> 7, sp = kk & 127;
      return a.B + (size_t)cb * A2T_B + (size_t)cj * A2T_CJ
           + (size_t)kh * A2T_KH + (size_t)n * 128 + sp;
    }
    if (V == 2) {
      int tau = kk >> 9, p = kk & 511;
      return a.B + (size_t)tau * 524288 + (size_t)n * 1024 + p;
    }
    if (V == 3) {
      int jn = n >> 9, o = n & 511;
      return a.B + (size_t)(jn + 1) * 524288 + (size_t)o * 1024 + kk;
    }
    if (V == 5) {
      // B[n][kk] = S^c^T[n][kk] from P
      return (kk < 512)
          ? a.Pb + (size_t)a.cidx * 524288 + (size_t)n * 512 + kk
          : a.Pb + (size_t)(a.cidx - 1) * 524288 + (size_t)n * 512 + (kk - 512);
    }
    // V6/V7: rows of S32 = [Top32 ; Top31]
    return (n < 512)
        ? a.B + (size_t)32 * 524288 + (size_t)n * 1024 + kk
        : a.B + (size_t)31 * 524288 + (size_t)(n - 512) * 1024 + kk;
  };

  auto stage = [&](int c, int k0) {
    if (V == 0) {
      int kk = k0 + ((lane >> 4) << 3);
      int lrowA = wv * 16 + (lane & 15);
      gll16(Ap + (size_t)(m0 + lrowA) * 512 + kk, smem + c * 4096 + wv * 512);
#pragma unroll
      for (int it = 0; it < 2; ++it) {
        int lrowB = (it * 8 + wv) * 16 + (lane & 15);
        gll16(a.B + (size_t)(n0 + lrowB) * 512 + kk,
              smem + 8192 + c * 8192 + (it * 8 + wv) * 512);
      }
    } else {
#pragma unroll
      for (int it = 0; it < 2; ++it) {
        int weff = wv + it * 4;
        gll16(gaddrA(it, k0), smem + c * 4096 + weff * 512);
        gll16(gaddrB(it, k0), smem + 8192 + c * 4096 + weff * 512);
      }
    }
  };

  if (kbeg < kend) stage(0, kbeg);
  __syncthreads();                 // drains the prologue stage
  int cur = 0;
  for (int k0 = kbeg; k0 < kend; k0 += 32) {
    if (k0 + 32 < kend) stage(cur ^ 1, k0 + 32);   // async prefetch next tile
    vshort8 af[4], bf_[4];
#pragma unroll
    for (int s = 0; s < 4; s++) {
      af[s] = *(const vshort8*)&smem[cur * 4096 +
                (((wr * 4 + s) * 4 + (lane >> 4)) * 16 + (lane & 15)) * 8];
      if (V == 0)
        bf_[s] = *(const vshort8*)&smem[8192 + cur * 8192 +
                  (((wc * 4 + s) * 4 + (lane >> 4)) * 16 + (lane & 15)) * 8];
      else
        bf_[s] = *(const vshort8*)&smem[8192 + cur * 4096 +
                  (((wc * 4 + s) * 4 + (lane >> 4)) * 16 + (lane & 15)) * 8];
    }
#pragma unroll
    for (int i = 0; i < 4; i++)
#pragma unroll
      for (int j = 0; j < 4; j++)
        acc[i][j] = __builtin_amdgcn_mfma_f32_16x16x32_bf16(af[i], bf_[j], acc[i][j], 0, 0, 0);
    __syncthreads();               // drains prefetch + protects buffer swap
    cur ^= 1;
  }

  // ---- epilogue ----
  if (V == 0 && bn < 96) {
    // 4 phases; phase p handles n-cols [n0+p*64, +64) via LDS transpose.
    const int strd = 136;
    const int b = m0 >> 10;
    const int cjw = (m0 & 1023) >> 7;
#pragma unroll
    for (int p = 0; p < 4; ++p) {
      __syncthreads();
      if (wc == p) {
#pragma unroll
        for (int i = 0; i < 4; i++) {
#pragma unroll
          for (int j = 0; j < 4; j++) {
            f32x4 v = acc[i][j];
            int mloc = wr * 64 + i * 16 + ((lane >> 4) << 2);  // sp in [0,128)
            int phys = j * 16 + (lane & 15);                   // n-off in [0,64)
            vshort4 pk = { (short)f2b(v[0]), (short)f2b(v[1]),
                           (short)f2b(v[2]), (short)f2b(v[3]) };
            *(vshort4*)&smem[phys * strd + mloc] = pk;
          }
        }
      }
      __syncthreads();
      int rowp = tid >> 3, t8 = tid & 7;
      int n = n0 + p * 64 + rowp;
      int o = n & 511, kh = n >> 9;
      u16* dst = a.A2T + (size_t)b * A2T_B + (size_t)cjw * A2T_CJ
               + (size_t)kh * A2T_KH + (size_t)o * 128 + t8 * 16;
      const u16* srcl = &smem[rowp * strd + t8 * 16];
      *(vuint4*)(dst)     = *(const vuint4*)(srcl);
      *(vuint4*)(dst + 8) = *(const vuint4*)(srcl + 8);
    }
    return;
  }

#pragma unroll
  for (int i = 0; i < 4; i++) {
    int em = m0 + wr * 64 + i * 16 + ((lane >> 4) << 2);
#pragma unroll
    for (int j = 0; j < 4; j++) {
      int n = n0 + wc * 64 + j * 16 + (lane & 15);
      f32x4 v = acc[i][j];
      if (V == 0) {
        int b = em >> 10, s = em & 1023;
        int jj = (n - 24576) >> 9, o = n & 511;
#pragma unroll
        for (int t = 0; t < 4; t++)
          a.Au[((size_t)(b * 3 + jj) * 1024 + (s + t)) * 512 + o] = f2b(v[t]);
      } else if (V == 1) {
        u16* C = a.Cb + (size_t)slot * 524288;
#pragma unroll
        for (int t = 0; t < 4; t++) C[(size_t)(em + t) * 512 + n] = f2b(v[t]);
      } else if (V == 2) {
        float* C = a.Cf + (size_t)zz * 1048576;
#pragma unroll
        for (int t = 0; t < 4; t++) C[(size_t)(em + t) * 512 + n] = v[t];
      } else if (V == 3) {
        int jj = n >> 9, oo = n & 511;
#pragma unroll
        for (int t = 0; t < 4; t++) {
          int m = em + t;
          if (m < a.M) {
            int b = m >> 5, c = m & 31;
            float zv = a.zf[(size_t)(jj * 64 + b * 32 + c) * 512 + oo];
            a.out[(size_t)b * 524288 + (size_t)(c * 32 + jj) * 512 + oo] = v[t] + zv;
          }
        }
      } else if (V == 5) {
        u16* C = a.Cb + (size_t)zz * 524288;
#pragma unroll
        for (int t = 0; t < 4; t++) C[(size_t)(em + t) * 1024 + n] = f2b(v[t]);
      } else if (V == 6) {
        int jrow = (n < 512) ? 31 : 30, oo = n & 511;
#pragma unroll
        for (int t = 0; t < 4; t++) {
          int m = em + t;
          if (m < 62) {
            int b = m & 1, c = m >> 1;
            a.Cf[(size_t)m * 1024 + n] =
                v[t] + a.zf[(size_t)(jrow * 64 + b * 32 + (c + 1)) * 512 + oo];
          }
        }
      } else { // V7: odd states
        int jrow = (n < 512) ? 31 : 30, oo = n & 511;
#pragma unroll
        for (int t = 0; t < 4; t++) {
          int m = em + t;
          if (m < 32) {
            int b = m & 1, k2 = m >> 1;
            float val = v[t] + a.zf[(size_t)(jrow * 64 + b * 32 + 2 * k2) * 512 + oo];
            a.Cb[(size_t)(b * 32 + 2 * k2 + 1) * 1024 + n] = f2b(val);
          }
        }
      }
    }
  }

  // V5 dual-write: P[c+1+zz][n][m] = C[m][n] via LDS transpose (2 passes)
  if (V == 5) {
    if (zz >= a.pthr) {
      const int strd = 136;
      u16* Pout = a.Pb + (size_t)(a.cidx + 1 + zz) * 524288;
#pragma unroll
      for (int p = 0; p < 2; ++p) {
        __syncthreads();
        if (wc == p) {
#pragma unroll
          for (int i = 0; i < 4; i++) {
#pragma unroll
            for (int j = 0; j < 4; j++) {
              f32x4 v = acc[i][j];
              int mloc = wr * 64 + i * 16 + ((lane >> 4) << 2);  // m-off [0,128)
              int phys = j * 16 + (lane & 15);                   // n-off [0,64)
              vshort4 pk = { (short)f2b(v[0]), (short)f2b(v[1]),
                             (short)f2b(v[2]), (short)f2b(v[3]) };
              *(vshort4*)&smem[phys * strd + mloc] = pk;
            }
          }
        }
        __syncthreads();
        int rowp = tid >> 2, t4 = tid & 3;
        u16* dst = Pout + (size_t)(n0 + p * 64 + rowp) * 512 + m0 + t4 * 32;
        const u16* srcl = &smem[rowp * strd + t4 * 32];
#pragma unroll
        for (int q = 0; q < 4; ++q)
          *(vuint4*)(dst + q * 8) = *(const vuint4*)(srcl + q * 8);
      }
    }
  }
}

// ---------------------------------------------------------------------------
// prep / glue kernels
// ---------------------------------------------------------------------------
// phis[tau*48 + kf]: kf<24 -> phi_s[tau,kf]; kf>=24 -> phi_s[tau,kf-24]*(-1)^tau
__global__ void k_prep_phis(const float* __restrict__ phi, const float* __restrict__ sigma,
                            float* __restrict__ phis) {
  int i = blockIdx.x * 256 + threadIdx.x;
  if (i >= 1024 * 48) return;
  int tau = i / 48, kf = i % 48, k = (kf >= 24) ? kf - 24 : kf;
  float v = phi[tau * 24 + k] * powf(sigma[k], 0.25f);
  if (kf >= 24 && (tau & 1)) v = -v;
  phis[i] = v;
}

// fused: X convert (vec4), W1 convert (vec4 x4 rounds), Wtoep build (vec8)
__global__ void k_prep_all(const float* __restrict__ u, const float* __restrict__ Mp,
                           const float* __restrict__ Mm, const float* __restrict__ Mu,
                           const float* __restrict__ phis,
                           u16* __restrict__ X, u16* __restrict__ W1,
                           u16* __restrict__ Wtoep) {
  int gid = blockIdx.x * 256 + threadIdx.x;   // [0, 1048576)
  if (gid < 262144) {
    int i4 = gid * 4;
    f32x4 v = *(const f32x4*)(u + i4);
    vshort4 pk = { (short)f2b(v[0]), (short)f2b(v[1]), (short)f2b(v[2]), (short)f2b(v[3]) };
    *(vshort4*)(X + i4) = pk;
  }
#pragma unroll
  for (int r = 0; r < 4; ++r) {
    int item = gid + r * 1048576;
    if (item < 3342336) {
      int i4 = item * 4;
      const float* src; int off;
      if (i4 < 6291456) { src = Mp; off = i4; }
      else if (i4 < 12582912) { src = Mm; off = i4 - 6291456; }
      else { src = Mu; off = i4 - 12582912; }
      f32x4 v = *(const f32x4*)(src + off);
      vshort4 pk = { (short)f2b(v[0]), (short)f2b(v[1]), (short)f2b(v[2]), (short)f2b(v[3]) };
      *(vshort4*)(W1 + i4) = pk;
    }
  }
  if (gid < 786432) {
    int i = gid * 8;
    int kap = i % 6144, row = i / 6144;
    int tp = row & 127, d = row >> 7;
    int kh = kap >> 7, sp = kap & 127;
    int tau0 = d * 128 + tp - sp;
    u16 vals[8];
#pragma unroll
    for (int e = 0; e < 8; ++e) {
      int tau = tau0 - e;
      vals[e] = (tau >= 0 && tau < 1024) ? f2b(phis[tau * 48 + kh]) : (u16)0;
    }
    *(vuint4*)(Wtoep + i) = *(const vuint4*)vals;
  }
}

// Top[0]=[I|0], Top[1]=[M1|M2]; P[0]=Top[0]^T, P[1]=Top[1]^T
__global__ void k_initTop(const float* __restrict__ my, u16* __restrict__ Top,
                          u16* __restrict__ P) {
  int i = blockIdx.x * 256 + threadIdx.x;
  if (i >= 2097152) return;
  if (i < 1048576) {
    int mat = i >> 19, rem = i & 524287, o = rem >> 10, k = rem & 1023;
    u16 v;
    if (mat == 0) v = (k == o) ? (u16)0x3F80 : (u16)0;
    else v = (k < 512) ? f2b(my[o * 512 + k]) : f2b(my[262144 + o * 512 + (k - 512)]);
    Top[i] = v;
  } else {
    int j = i - 1048576;
    int mat = j >> 19, rem = j & 524287, n = rem >> 9, m = rem & 511;
    u16 v;
    if (mat == 0) v = (n == m) ? (u16)0x3F80 : (u16)0;
    else v = (n < 512) ? f2b(my[m * 512 + n]) : f2b(my[262144 + m * 512 + (n - 512)]);
    P[(size_t)mat * 524288 + (size_t)n * 512 + m] = v;
  }
}

__device__ __forceinline__ void addp(float* acc, vuint4 v) {
  const unsigned int* vu = (const unsigned int*)&v;
#pragma unroll
  for (int e = 0; e < 4; ++e) {
    unsigned int pw = vu[e];
    acc[2 * e]     += __builtin_bit_cast(float, (pw & 0xffffu) << 16);
    acc[2 * e + 1] += __builtin_bit_cast(float, pw & 0xffff0000u);
  }
}

// ybf[b,t,og*8..] = sum_j Au[b,j,t-j,:] + (t>=2 ? valid bf16 conv partials : 0)
__global__ void k_combine(const u16* __restrict__ parts, const u16* __restrict__ Au,
                          u16* __restrict__ ybf) {
  int i = blockIdx.x * 256 + threadIdx.x;
  if (i >= 131072) return;
  int og = i & 63, t = (i >> 6) & 1023, b = i >> 16;
  float acc[8];
#pragma unroll
  for (int e = 0; e < 8; ++e) acc[e] = 0.f;
#pragma unroll
  for (int j = 0; j < 3; j++)
    if (t >= j)
      addp(acc, *(const vuint4*)(Au + ((size_t)(b * 3 + j) * 1024 + (t - j)) * 512 + og * 8));
  if (t >= 2) {
    int tp = t - 2, bmv = tp >> 7;
#pragma unroll
    for (int g = 0; g < 8; ++g) {
      if ((g & 1) != b) continue;
      const u16* base = parts + (size_t)(g * 8) * 524288 + (size_t)tp * 512 + og * 8;
      for (int j = 0; j <= bmv; ++j)
        addp(acc, *(const vuint4*)(base + (size_t)j * 524288));
    }
  }
  u16 o16[8];
#pragma unroll
  for (int e = 0; e < 8; ++e) o16[e] = f2b(acc[e]);
  *(vuint4*)(ybf + ((size_t)(b * 1024 + t)) * 512 + og * 8) = *(vuint4*)o16;
}

// fused: zf reduce + Wm extraction + bnd/Abnd zero-init
__global__ void k_zred(const float* __restrict__ zp, float* __restrict__ z,
                       u16* __restrict__ Wm, float* __restrict__ bnd,
                       u16* __restrict__ Abnd) {
  int i = blockIdx.x * 256 + threadIdx.x;
  if (i < 2048) bnd[i] = 0.f;
  if (i < 1024) { Abnd[i] = 0; Abnd[32768 + i] = 0; }
  if (i >= 1048576) return;
  int nsum = (i >> 16) + 1;        // bm = i>>16 in [0,16)
  float s = 0.f;
  for (int j = 0; j < nsum; ++j) s += zp[(size_t)j * 1048576 + i];
  z[i] = s;
  int m = i >> 9, jj = m >> 6, rem = m & 63, b = rem >> 5, c = rem & 31, oo = i & 511;
  if (jj == 31) Wm[(size_t)((c << 1) | b) * 1024 + oo] = f2b(s);
  if (jj == 30) Wm[(size_t)((c << 1) | b) * 1024 + 512 + oo] = f2b(s);
}

// even chain step k: E_{k+1} = S64 E_k + u_{2k}; emit Abnd row (b*32+2k+2)
// S64 rows: top = Top slot34, bottom = Top slot33
__global__ __launch_bounds__(256) void k_bnd2(const u16* __restrict__ Top,
                                              const float* __restrict__ ubuf,
                                              float* __restrict__ bnd,
                                              u16* __restrict__ Abnd, int k) {
  __shared__ float st[2048];
  int tid = threadIdx.x;
  const float* s0 = bnd + (size_t)k * 2048;
  for (int j = tid; j < 2048; j += 256) st[j] = s0[j];
  __syncthreads();
  int q4 = blockIdx.x * 256 + tid;  // [0,8192)
  int q = q4 >> 2, quarter = q4 & 3;
  int b = q >> 10, kk = q & 1023;
  const u16* row = (kk < 512) ? Top + (size_t)34 * 524288 + (size_t)kk * 1024
                              : Top + (size_t)33 * 524288 + (size_t)(kk - 512) * 1024;
  const float* stb = st + b * 1024 + quarter * 256;
  const u16* rp = row + quarter * 256;
  float sum = 0.f;
  for (int t = 0; t < 32; ++t) {
    vuint4 v = *(const vuint4*)(rp + t * 8);
    const unsigned int* vu = (const unsigned int*)&v;
#pragma unroll
    for (int e = 0; e < 4; ++e) {
      unsigned int pw = vu[e];
      float lo = __builtin_bit_cast(float, (pw & 0xffffu) << 16);
      float hi = __builtin_bit_cast(float, pw & 0xffff0000u);
      sum += lo * stb[t * 8 + e * 2] + hi * stb[t * 8 + e * 2 + 1];
    }
  }
  sum += __shfl_xor(sum, 1);
  sum += __shfl_xor(sum, 2);
  if (quarter == 0) {
    float s = sum + ubuf[(size_t)(4 * k + b) * 1024 + kk];
    bnd[(size_t)(k + 1) * 2048 + b * 1024 + kk] = s;
    Abnd[(size_t)(b * 32 + 2 * k + 2) * 1024 + kk] = f2b(s);
  }
}

// ---------------------------------------------------------------------------
extern "C" void kernel_launch(void* const* d_in, const int* in_sizes, int n_in,
                              void* d_out, int out_size, void* d_ws, size_t ws_size,
                              hipStream_t stream) {
  const float* u     = (const float*)d_in[0];
  const float* Mu    = (const float*)d_in[1];
  const float* Mp    = (const float*)d_in[2];
  const float* Mm    = (const float*)d_in[3];
  const float* my    = (const float*)d_in[4];
  const float* sigma = (const float*)d_in[5];
  const float* phi   = (const float*)d_in[6];
  float* out = (float*)d_out;

  char* ws = (char*)d_ws;
  size_t off = 0;
  auto alc = [&](size_t b) { size_t p = off; off = (off + b + 255) & ~(size_t)255; return p; };
  u16*  X     = (u16*)(ws + alc(2097152));
  u16*  Wtoep = (u16*)(ws + alc(12582912));    // 8 d x 128 x 6144
  u16*  A2T   = (u16*)(ws + alc(100663296));   // [b][cj][kh][o][sp]
  u16*  Au    = (u16*)(ws + alc(6291456));
  u16*  W1    = (u16*)(ws + alc(26738688));    // 26112x512; parts region spans W1+tail
  char* ptail = ws + alc(40370176); (void)ptail; // W1+tail = 64 MiB exactly
  float* phis = (float*)(ws + alc(196608));    // [1024 tau][48 kf] f32
  float* bnd  = (float*)(ws + alc(131072));    // 16 even states x 2048 f32
  u16*  Abnd  = (u16*)(ws + alc(131072));      // 64 x 1024 bf16 boundary states
  u16*  Wm    = (u16*)(ws + alc(131072));      // 64 x 1024 bf16 w_c
  float* ubuf = (float*)(ws + alc(262144));    // 64 x 1024 f32 u_c
  u16*  zpad  = (u16*)(ws + alc(32768));       // zero page for predicated lanes
  if (off > ws_size) return;
  // lifetime-disjoint aliases:
  u16*  partsBf = (u16*)W1;                    // 64 conv slots x [1024][512] bf16 = 64 MiB
  float* zparts = (float*)W1;                  // 16 zgemm slots x 4 MiB f32 = 64 MiB
  u16*  ybf = A2T;                             // 2 MiB (after conv)
  float* zf = (float*)((char*)A2T + (4 << 20));
  u16*  Top = (u16*)((char*)A2T + (size_t)(8 << 20));   // 35 slots x 1 MiB (0..32,33=H63,34=H64)
  u16*  P   = (u16*)((char*)A2T + (size_t)(44 << 20));  // 33 slots x 1 MiB (Top^T)

  hipMemsetAsync(zpad, 0, 32768, stream);

  // prep
  k_prep_phis<<<dim3(192), 256, 0, stream>>>(phi, sigma, phis);
  k_prep_all<<<dim3(4096), 256, 0, stream>>>(u, Mp, Mm, Mu, phis, X, W1, Wtoep);

  // GEMM1: projections; 128x256 tile, 512 threads, 1-D XCD-chunked grid
  {
    GB g{}; g.A = X; g.B = W1; g.A2T = A2T; g.Au = Au; g.zp = zpad;
    g.M = 2048; g.N = 26112;
    g2<0><<<dim3(1632), 512, 0, stream>>>(g);
  }
  // CONV: global Wtoep strips, locality-ordered XCD-chunked grid, splitK=8
  {
    GB g{}; g.A = Wtoep; g.B = A2T; g.Cb = partsBf; g.zp = zpad;
    g.M = 1024; g.N = 512;
    g2<1><<<dim3(1152), 256, 0, stream>>>(g);
  }
  k_combine<<<dim3(512), 256, 0, stream>>>(partsBf, Au, ybf);

  // companion-power stack Top[0..32] (+P at needed indices), then slots 33/34
  k_initTop<<<dim3(8192), 256, 0, stream>>>(my, Top, P);
  {
    const int cs[5] = {1, 2, 4, 8, 16};
    for (int li = 0; li < 5; ++li) {
      int c = cs[li];
      GB s{}; s.A = Top + 524288; s.Cb = Top + (size_t)(c + 1) * 524288;
      s.Pb = P; s.cidx = c; s.pthr = c - 2;
      s.zp = zpad; s.M = 512; s.N = 1024;
      g2<5><<<dim3(8, 4, c), 256, 0, stream>>>(s);
    }
    // slot33 = Top[31]*S^32 (=H63), slot34 = Top[32]*S^32 (=H64)
    GB s{}; s.A = Top + (size_t)31 * 524288;
    s.Cb = Top + (size_t)33 * 524288;
    s.Pb = P; s.cidx = 32; s.pthr = 99;
    s.zp = zpad; s.M = 512; s.N = 1024;
    g2<5><<<dim3(8, 4, 2), 256, 0, stream>>>(s);
  }

  // within-chunk solve: z = Tri(H) y; compact triangular grid, 16 slices
  {
    GB g{}; g.A = ybf; g.B = Top; g.Cf = zparts; g.zp = zpad;
    g.M = 2048; g.N = 512;
    g2<2><<<dim3(544), 256, 0, stream>>>(g);
  }
  k_zred<<<dim3(4096), 256, 0, stream>>>(zparts, zf, Wm, bnd, Abnd);

  // boundary chain: u_c precompute, 15 even steps, batched odd fill
  {
    GB g{}; g.A = Wm; g.B = Top; g.Cf = ubuf; g.zf = zf; g.zp = zpad;
    g.M = 64; g.N = 1024;
    g2<6><<<dim3(8, 1, 1), 256, 0, stream>>>(g);
  }
  for (int k = 0; k < 15; ++k)
    k_bnd2<<<dim3(32), 256, 0, stream>>>(Top, ubuf, bnd, Abnd, k);
  {
    GB g{}; g.A = Abnd; g.B = Top; g.Cb = Abnd; g.zf = zf; g.zp = zpad;
    g.M = 32; g.N = 1024;
    g2<7><<<dim3(8, 1, 1), 256, 0, stream>>>(g);
  }

  // fixup: out = z + [H_{j+1}|G_j] @ Abnd
  {
    GB g{}; g.A = Abnd; g.B = Top; g.zf = zf; g.out = out; g.zp = zpad;
    g.M = 64; g.N = 16384;
    g2<3><<<dim3(128, 1, 1), 256, 0, stream>>>(g);
  }
}